// Round 11
// baseline (178.625 us; speedup 1.0000x reference)
//
#include <hip/hip_runtime.h>
#include <stdint.h>
#include <stddef.h>

// ---------------------------------------------------------------------------
// SwinBlock: rearrange -> QKV proj -> 8-head attention (L=256, D=32)
//            -> out proj -> LayerNorm -> inverse rearrange
// bf16 MFMA internal compute, fp32 in/out. MI355X gfx950.
// R11: k_qkv reverted EXACTLY to R8 (best measured: 48us; single-buffer
//      BK=64 + both-sides swizzle). k_attn v8 = R8 streaming structure but
//      accS (32 AGPRs) replaced by R5-style VALU sum + one shfl_xor ->
//      total regs ~95, __launch_bounds__(256,4) -> 4 blocks/CU (2x TLP on a
//      latency-bound kernel). k_out unchanged.
// ---------------------------------------------------------------------------

typedef __attribute__((ext_vector_type(8))) short bf16x8;   // 8 bf16 in 4 VGPRs
typedef __attribute__((ext_vector_type(4))) float f32x4;
typedef __attribute__((ext_vector_type(16))) float f32x16;
typedef __attribute__((ext_vector_type(4))) unsigned u32x4;
typedef __attribute__((ext_vector_type(2))) unsigned u32x2;
typedef unsigned short bf16u;

#define LOG2E 1.4426950408889634f
#define MFMA32(a, b, c) __builtin_amdgcn_mfma_f32_32x32x16_bf16(a, b, c, 0, 0, 0)

__device__ __forceinline__ bf16u f2b(float f) {
  uint32_t u = __float_as_uint(f);
  u += 0x7fffu + ((u >> 16) & 1u);          // round-to-nearest-even
  return (bf16u)(u >> 16);
}
__device__ __forceinline__ float b2f(bf16u s) {
  return __uint_as_float(((uint32_t)s) << 16);
}

__device__ __forceinline__ void gload_lds16(const void* g, void* l) {
  __builtin_amdgcn_global_load_lds((__attribute__((address_space(1))) void*)(g),
                                   (__attribute__((address_space(3))) void*)(l),
                                   16, 0, 0);
}

// pack 2 f32 -> u32 of 2 bf16 (low = a, high = b), RNE
__device__ __forceinline__ unsigned cvtpk(float a, float b) {
  unsigned r;
  asm("v_cvt_pk_bf16_f32 %0, %1, %2" : "=v"(r) : "v"(a), "v"(b));
  return r;
}

// fast reciprocal (~1 ulp)
__device__ __forceinline__ float frcp(float x) {
  float r;
  asm("v_rcp_f32 %0, %1" : "=v"(r) : "v"(x));
  return r;
}

// exchange upper-half lanes of a with lower-half lanes of b (lane^32 pairing)
__device__ __forceinline__ void swap32(unsigned a, unsigned b, bool hi,
                                       unsigned& x, unsigned& y) {
#if __has_builtin(__builtin_amdgcn_permlane32_swap)
  typedef __attribute__((ext_vector_type(2))) unsigned uint2v;
  uint2v r = __builtin_amdgcn_permlane32_swap(a, b, false, false);
  x = r.x;
  y = r.y;
#else
  unsigned as = (unsigned)__shfl_xor((int)a, 32);
  unsigned bs = (unsigned)__shfl_xor((int)b, 32);
  x = hi ? bs : a;
  y = hi ? b : as;
#endif
}

// --------------------------- weight convert fp32->bf16 (merged) ------------
__global__ __launch_bounds__(256) void k_convert2(const float* __restrict__ s1,
                                                  const float* __restrict__ s2,
                                                  bf16u* __restrict__ d1,
                                                  bf16u* __restrict__ d2) {
  int i = blockIdx.x * 256 + threadIdx.x;
  if (i < 768 * 256) d1[i] = f2b(s1[i]);
  else { int j = i - 768 * 256; d2[j] = f2b(s2[j]); }
}

// --------------------------- K1: rearrange x -> Tb -------------------------
// Tb[i][c], i = n*256 + l, n = b*64 + h2*8 + w2, l = h1*16 + w1
__global__ __launch_bounds__(256) void k_rearrange(const float* __restrict__ x,
                                                   bf16u* __restrict__ Tb) {
  const int bid = blockIdx.x;
  const int ct = bid & 7, hh = (bid >> 3) & 127, b = bid >> 10;
  const int c0 = ct * 32;
  const int h1 = hh >> 3, h2 = hh & 7;
  __shared__ float tile[32][129];
  for (int e = threadIdx.x; e < 4096; e += 256) {
    int cc = e >> 7, ww = e & 127;   // coalesced x reads (512B rows)
    tile[cc][ww] = x[(((size_t)(b * 256 + c0 + cc)) * 128 + hh) * 128 + ww];
  }
  __syncthreads();
  for (int e = threadIdx.x; e < 4096; e += 256) {
    int ww = e >> 5, cc = e & 31;    // contiguous-in-c writes
    int w1 = ww >> 3, w2 = ww & 7;
    int i = ((b * 64 + h2 * 8 + w2) << 8) | (h1 * 16 + w1);
    Tb[(size_t)i * 256 + c0 + cc] = f2b(tile[cc][ww]);
  }
}

// --------------------------- K2: QKV GEMM (R8 form) ------------------------
// C[i,o] = sum_k Tb[i,k]*W[o,k] + bias[o]; 128x128 tile, BK=64, 4 waves (2x2)
// LDS rows = 64 bf16 = 128B (bank-period). Chunk swizzle c^(row&7) on the
// global SOURCE of global_load_lds and on ds_read (both-sides, rule #21).
// Q gets qscale*LOG2E folded in. V stored transposed [nh*32+d][kv], packed.
__global__ __launch_bounds__(256) void k_qkv(const bf16u* __restrict__ Tb,
                                             const bf16u* __restrict__ Wb,
                                             const float* __restrict__ bias,
                                             bf16u* __restrict__ Qb,
                                             bf16u* __restrict__ Kb,
                                             bf16u* __restrict__ Vtb) {
  __shared__ bf16u As[128 * 64];   // 16 KB
  __shared__ bf16u Bs[128 * 64];   // 16 KB
  // bijective XCD-chunked swizzle: 3072 blocks = 8 XCD x 384
  const int bid0 = blockIdx.x;
  const int bid = (bid0 & 7) * 384 + (bid0 >> 3);
  const int o0 = (bid % 6) * 128;          // o-tile fastest: A-panel L2 reuse
  const int i0 = (bid / 6) * 128;
  const int seg = o0 >> 8;                 // 0=Q 1=K 2=V, uniform per block
  const int t = threadIdx.x;
  const int lane = t & 63, lo = lane & 15, hi = lane >> 4;
  const int w = t >> 6, wr = w >> 1, wc = w & 1;
  const int rr = t >> 3, cc8 = t & 7;      // staging: row-in-32, chunk 0..7
  f32x4 acc[4][4] = {};
  for (int k0 = 0; k0 < 256; k0 += 64) {
    __syncthreads();
#pragma unroll
    for (int j = 0; j < 4; ++j) {
      const int row = j * 32 + rr;
      const int sc = (cc8 ^ (row & 7)) * 8;                 // swizzled source
      bf16u* const da = As + (j * 32 + w * 8) * 64;         // wave-uniform dest
      bf16u* const db = Bs + (j * 32 + w * 8) * 64;
      gload_lds16(Tb + (size_t)(i0 + row) * 256 + k0 + sc, da);
      gload_lds16(Wb + (size_t)(o0 + row) * 256 + k0 + sc, db);
    }
    __syncthreads();
#pragma unroll
    for (int ks = 0; ks < 2; ++ks) {
      bf16x8 af[4], bf_[4];
#pragma unroll
      for (int m = 0; m < 4; ++m) {
        const int row = wr * 64 + m * 16 + lo;
        const int c = (ks * 4 + hi) ^ (lo & 7);
        af[m] = *(const bf16x8*)&As[row * 64 + c * 8];
      }
#pragma unroll
      for (int nn = 0; nn < 4; ++nn) {
        const int row = wc * 64 + nn * 16 + lo;
        const int c = (ks * 4 + hi) ^ (lo & 7);
        bf_[nn] = *(const bf16x8*)&Bs[row * 64 + c * 8];
      }
#pragma unroll
      for (int m = 0; m < 4; ++m)
#pragma unroll
        for (int nn = 0; nn < 4; ++nn)
          acc[m][nn] = __builtin_amdgcn_mfma_f32_16x16x32_bf16(af[m], bf_[nn], acc[m][nn], 0, 0, 0);
    }
  }
  const float oscale = (seg == 0) ? (0.17677669529663687f * LOG2E) : 1.0f;
#pragma unroll
  for (int m = 0; m < 4; ++m) {
#pragma unroll
    for (int nn = 0; nn < 4; ++nn) {
      const int o = o0 + wc * 64 + nn * 16 + lo;
      const int within = o & 255, head = within >> 5, dd = within & 31;
      const float bia = bias[o];
      const int tok0 = i0 + wr * 64 + m * 16 + hi * 4;
      const int nt = tok0 >> 8, ls0 = tok0 & 255;
      if (seg == 2) {        // transposed [nh*32+d][kv], 4 kv contiguous -> 8B
        float v0 = acc[m][nn][0] + bia, v1 = acc[m][nn][1] + bia;
        float v2 = acc[m][nn][2] + bia, v3 = acc[m][nn][3] + bia;
        u32x2 pkd = {cvtpk(v0, v1), cvtpk(v2, v3)};
        *(u32x2*)(Vtb + ((size_t)((nt * 8 + head) * 32 + dd)) * 256 + ls0) = pkd;
      } else {
        bf16u* const dst = (seg == 0) ? Qb : Kb;
#pragma unroll
        for (int r = 0; r < 4; ++r) {
          float v = (acc[m][nn][r] + bia) * oscale;
          dst[((size_t)((nt * 8 + head) * 256 + ls0 + r)) * 32 + dd] = f2b(v);
        }
      }
    }
  }
}

// --------------------------- K3: attention (v8) ----------------------------
// one block per (n,head); 4 independent waves x 64 q-rows (2 subtiles of 32).
// Swapped QK^T (32x32x16), unnormalized softmax (logits pre-scaled by
// qscale*LOG2E at k_qkv; max cancels). Row-sum on VALU (16 adds + 1 shfl)
// to keep register footprint ~95 -> 4+ blocks/CU (latency-bound kernel).
__global__ __launch_bounds__(256, 4) void k_attn(const bf16u* __restrict__ Qb,
                                                 const bf16u* __restrict__ Kb,
                                                 const bf16u* __restrict__ Vtb,
                                                 bf16u* __restrict__ Ob) {
  const int nh = blockIdx.x;
  const int n = nh >> 3, h = nh & 7;
  const bf16u* Qp = Qb + (size_t)nh * 8192;
  const bf16u* Kp = Kb + (size_t)nh * 8192;
  const bf16u* Vp = Vtb + (size_t)nh * 8192;   // [32 d][256 kv]
  const int t = threadIdx.x, w = t >> 6, lane = t & 63;
  const int l31 = lane & 31;
  const bool hi5 = (lane & 32) != 0;

  // Q fragments: B-operand of QK^T.  B[k=d][col=q] = Q[q][d]
  bf16x8 qf[2][2];
#pragma unroll
  for (int qs = 0; qs < 2; ++qs)
#pragma unroll
    for (int dh = 0; dh < 2; ++dh)
      qf[qs][dh] = *(const bf16x8*)(Qp + (size_t)(w * 64 + qs * 32 + l31) * 32 +
                                    dh * 16 + (hi5 ? 8 : 0));

  // K A-frag base: A[row=kv][k=d]; V B-frag base: B[k=kv][col=d] = Vt[d][kv]
  const bf16u* kbase = Kp + (size_t)l31 * 32 + (hi5 ? 8 : 0);
  const bf16u* vbase = Vp + (size_t)l31 * 256 + (hi5 ? 8 : 0);

  bf16x8 kf0 = *(const bf16x8*)(kbase);
  bf16x8 kf1 = *(const bf16x8*)(kbase + 16);
  bf16x8 vf0 = *(const bf16x8*)(vbase);
  bf16x8 vf1 = *(const bf16x8*)(vbase + 16);

  f32x16 accO[2] = {};
  float rsum[2] = {0.f, 0.f};

#pragma unroll
  for (int kt = 0; kt < 8; ++kt) {
    // depth-1 prefetch of next K/V fragments ((kt+1)&7 wraps harmlessly)
    const int nkt = (kt + 1) & 7;
    bf16x8 nk0 = *(const bf16x8*)(kbase + nkt * 1024);
    bf16x8 nk1 = *(const bf16x8*)(kbase + nkt * 1024 + 16);
    bf16x8 nv0 = *(const bf16x8*)(vbase + nkt * 32);
    bf16x8 nv1 = *(const bf16x8*)(vbase + nkt * 32 + 16);

#pragma unroll
    for (int qs = 0; qs < 2; ++qs) {
      f32x16 s = {};
      s = MFMA32(kf0, qf[qs][0], s);
      s = MFMA32(kf1, qf[qs][1], s);
      // --- unnormalized softmax: p = exp2(s); sum on VALU; pack pairs ---
      float ts0 = 0.f, ts1 = 0.f;
      unsigned pk[8];
#pragma unroll
      for (int jp = 0; jp < 8; ++jp) {
        float p0 = exp2f(s[2 * jp]);
        float p1 = exp2f(s[2 * jp + 1]);
        ts0 += p0;
        ts1 += p1;
        pk[jp] = cvtpk(p0, p1);
      }
      float ts = ts0 + ts1;
      ts += __shfl_xor(ts, 32);     // both halves hold full 32-kv sum for q=l31
      rsum[qs] += ts;
      // --- redistribute packed P to PV A-fragment layout ---
      unsigned x0, x1, x2, x3, y0, y1, y2, y3;
      swap32(pk[0], pk[2], hi5, x0, x2);
      swap32(pk[1], pk[3], hi5, x1, x3);
      swap32(pk[4], pk[6], hi5, y0, y2);
      swap32(pk[5], pk[7], hi5, y1, y3);
      u32x4 pa0 = {x0, x1, x2, x3};
      u32x4 pa1 = {y0, y1, y2, y3};
      const bf16x8 a0 = __builtin_bit_cast(bf16x8, pa0);
      const bf16x8 a1 = __builtin_bit_cast(bf16x8, pa1);
      __builtin_amdgcn_s_setprio(1);
      accO[qs] = MFMA32(a0, vf0, accO[qs]);
      accO[qs] = MFMA32(a1, vf1, accO[qs]);
      __builtin_amdgcn_s_setprio(0);
    }
    kf0 = nk0;
    kf1 = nk1;
    vf0 = nv0;
    vf1 = nv1;
  }
  // --- epilogue: normalize rows, write O[token][h*32+d] ---
#pragma unroll
  for (int qs = 0; qs < 2; ++qs) {
    float rn = frcp(rsum[qs]);
#pragma unroll
    for (int r = 0; r < 16; ++r) {
      int row = (r & 3) + 8 * (r >> 2) + ((lane & 32) >> 3);
      float c = __shfl(rn, (lane & 32) | row);
      float o = accO[qs][r] * c;
      Ob[((size_t)(n * 256 + w * 64 + qs * 32 + row)) * 256 + h * 32 + l31] = f2b(o);
    }
  }
}

// --------------------------- K4: out proj + LayerNorm (R7/R8 form) ---------
// 64 tokens x all 256 channels per block; BK=64 + chunk swizzle; LN fused.
__global__ __launch_bounds__(256) void k_out(const bf16u* __restrict__ Ob,
                                             const bf16u* __restrict__ Wb,
                                             const float* __restrict__ bias,
                                             const float* __restrict__ lnw,
                                             const float* __restrict__ lnb,
                                             bf16u* __restrict__ On) {
  __shared__ bf16u As[64 * 64];    // 8 KB
  __shared__ bf16u Bs[256 * 64];   // 32 KB
  __shared__ float red[64][4][2];
  const int i0 = blockIdx.x * 64;
  const int t = threadIdx.x, w = t >> 6, lane = t & 63, lo = lane & 15, hi = lane >> 4;
  const int rr = t >> 3, cc8 = t & 7;
  f32x4 acc[4][4] = {};
  for (int k0 = 0; k0 < 256; k0 += 64) {
    __syncthreads();
#pragma unroll
    for (int j = 0; j < 2; ++j) {
      const int row = j * 32 + rr;
      const int sc = (cc8 ^ (row & 7)) * 8;
      gload_lds16(Ob + (size_t)(i0 + row) * 256 + k0 + sc,
                  As + (j * 32 + w * 8) * 64);
    }
#pragma unroll
    for (int j = 0; j < 8; ++j) {
      const int row = j * 32 + rr;
      const int sc = (cc8 ^ (row & 7)) * 8;
      gload_lds16(Wb + (size_t)row * 256 + k0 + sc,
                  Bs + (j * 32 + w * 8) * 64);
    }
    __syncthreads();
#pragma unroll
    for (int ks = 0; ks < 2; ++ks) {
      bf16x8 af[4], bf_[4];
#pragma unroll
      for (int m = 0; m < 4; ++m) {
        const int row = m * 16 + lo;
        const int c = (ks * 4 + hi) ^ (lo & 7);
        af[m] = *(const bf16x8*)&As[row * 64 + c * 8];
      }
#pragma unroll
      for (int nn = 0; nn < 4; ++nn) {
        const int row = w * 64 + nn * 16 + lo;
        const int c = (ks * 4 + hi) ^ (lo & 7);
        bf_[nn] = *(const bf16x8*)&Bs[row * 64 + c * 8];
      }
#pragma unroll
      for (int m = 0; m < 4; ++m)
#pragma unroll
        for (int nn = 0; nn < 4; ++nn)
          acc[m][nn] = __builtin_amdgcn_mfma_f32_16x16x32_bf16(af[m], bf_[nn], acc[m][nn], 0, 0, 0);
    }
  }
#pragma unroll
  for (int m = 0; m < 4; ++m)
#pragma unroll
    for (int nn = 0; nn < 4; ++nn) {
      float bia = bias[w * 64 + nn * 16 + lo];
#pragma unroll
      for (int r = 0; r < 4; ++r) acc[m][nn][r] += bia;
    }
#pragma unroll
  for (int m = 0; m < 4; ++m)
#pragma unroll
    for (int r = 0; r < 4; ++r) {
      float sv = acc[m][0][r] + acc[m][1][r] + acc[m][2][r] + acc[m][3][r];
      float sq = acc[m][0][r] * acc[m][0][r] + acc[m][1][r] * acc[m][1][r] +
                 acc[m][2][r] * acc[m][2][r] + acc[m][3][r] * acc[m][3][r];
      sv += __shfl_xor(sv, 1); sq += __shfl_xor(sq, 1);
      sv += __shfl_xor(sv, 2); sq += __shfl_xor(sq, 2);
      sv += __shfl_xor(sv, 4); sq += __shfl_xor(sq, 4);
      sv += __shfl_xor(sv, 8); sq += __shfl_xor(sq, 8);
      if (lo == 0) {
        red[m * 16 + hi * 4 + r][w][0] = sv;
        red[m * 16 + hi * 4 + r][w][1] = sq;
      }
    }
  __syncthreads();
#pragma unroll
  for (int m = 0; m < 4; ++m)
#pragma unroll
    for (int r = 0; r < 4; ++r) {
      int row = m * 16 + hi * 4 + r;
      float S  = red[row][0][0] + red[row][1][0] + red[row][2][0] + red[row][3][0];
      float Q2 = red[row][0][1] + red[row][1][1] + red[row][2][1] + red[row][3][1];
      float mu = S * 0.00390625f;
      float var = Q2 * 0.00390625f - mu * mu;
      float rstd = rsqrtf(var + 1e-5f);
#pragma unroll
      for (int nn = 0; nn < 4; ++nn) {
        int oc = w * 64 + nn * 16 + lo;
        float o = (acc[m][nn][r] - mu) * rstd * lnw[oc] + lnb[oc];
        On[(size_t)(i0 + row) * 256 + oc] = f2b(o);
      }
    }
}

// --------------------------- K5: inverse rearrange -------------------------
__global__ __launch_bounds__(256) void k_unrearrange(const bf16u* __restrict__ On,
                                                     float* __restrict__ y) {
  const int bid = blockIdx.x;
  const int ct = bid & 7, hh = (bid >> 3) & 127, b = bid >> 10;
  const int c0 = ct * 32;
  const int h1 = hh >> 3, h2 = hh & 7;
  __shared__ float tile[32][129];
  for (int e = threadIdx.x; e < 4096; e += 256) {
    int ww = e >> 5, cc = e & 31;
    int w1 = ww >> 3, w2 = ww & 7;
    int i = ((b * 64 + h2 * 8 + w2) << 8) | (h1 * 16 + w1);
    tile[cc][ww] = b2f(On[(size_t)i * 256 + c0 + cc]);
  }
  __syncthreads();
  for (int e = threadIdx.x; e < 4096; e += 256) {
    int cc = e >> 7, ww = e & 127;
    y[(((size_t)(b * 256 + c0 + cc)) * 128 + hh) * 128 + ww] = tile[cc][ww];
  }
}

// --------------------------- launch ----------------------------------------
extern "C" void kernel_launch(void* const* d_in, const int* in_sizes, int n_in,
                              void* d_out, int out_size, void* d_ws, size_t ws_size,
                              hipStream_t stream) {
  const float* x     = (const float*)d_in[0];
  const float* w_qkv = (const float*)d_in[1];
  const float* b_qkv = (const float*)d_in[2];
  const float* w_out = (const float*)d_in[3];
  const float* b_out = (const float*)d_in[4];
  const float* ln_w  = (const float*)d_in[5];
  const float* ln_b  = (const float*)d_in[6];
  float* y = (float*)d_out;

  const size_t SEG = 33554432;   // 16.7M bf16 elements = 32 MiB
  char* ws = (char*)d_ws;
  if (ws_size < 5 * SEG + 768 * 256 * 2 + 256 * 256 * 2) return;  // diagnostic fail
  bf16u* Tb = (bf16u*)(ws);                 // rearranged tokens; reused as On
  bf16u* Qb = (bf16u*)(ws + SEG);
  bf16u* Kb = (bf16u*)(ws + 2 * SEG);
  bf16u* Vtb = (bf16u*)(ws + 3 * SEG);      // transposed V: [nh][32 d][256 kv]
  bf16u* Ob = (bf16u*)(ws + 4 * SEG);
  bf16u* Wqkvb = (bf16u*)(ws + 5 * SEG);
  bf16u* Woutb = (bf16u*)(ws + 5 * SEG + 768 * 256 * 2);
  bf16u* On = Tb;

  k_convert2<<<1024, 256, 0, stream>>>(w_qkv, w_out, Wqkvb, Woutb);
  k_rearrange<<<4096, 256, 0, stream>>>(x, Tb);
  k_qkv<<<3072, 256, 0, stream>>>(Tb, Wqkvb, b_qkv, Qb, Kb, Vtb);
  k_attn<<<2048, 256, 0, stream>>>(Qb, Kb, Vtb, Ob);
  k_out<<<1024, 256, 0, stream>>>(Ob, Woutb, b_out, ln_w, ln_b, On);
  k_unrearrange<<<4096, 256, 0, stream>>>(On, y);
}

// Round 12
// 170.789 us; speedup vs baseline: 1.0459x; 1.0459x over previous
//
#include <hip/hip_runtime.h>
#include <stdint.h>
#include <stddef.h>

// ---------------------------------------------------------------------------
// SwinBlock: rearrange -> QKV proj -> 8-head attention (L=256, D=32)
//            -> out proj -> LayerNorm -> inverse rearrange
// bf16 MFMA internal compute, fp32 in/out. MI355X gfx950.
// R12: best-measured configuration (R8) restored exactly, plus:
//      - k_attn: hoisted zero accumulator (no per-tile f32x16 re-init)
//      - k_pre: weight-convert + rearrange merged into one launch
//      k_qkv / k_out / k_unrearrange byte-identical to R8.
// ---------------------------------------------------------------------------

typedef __attribute__((ext_vector_type(8))) short bf16x8;   // 8 bf16 in 4 VGPRs
typedef __attribute__((ext_vector_type(4))) float f32x4;
typedef __attribute__((ext_vector_type(16))) float f32x16;
typedef __attribute__((ext_vector_type(4))) unsigned u32x4;
typedef __attribute__((ext_vector_type(2))) unsigned u32x2;
typedef unsigned short bf16u;

#define LOG2E 1.4426950408889634f
#define MFMA32(a, b, c) __builtin_amdgcn_mfma_f32_32x32x16_bf16(a, b, c, 0, 0, 0)

__device__ __forceinline__ bf16u f2b(float f) {
  uint32_t u = __float_as_uint(f);
  u += 0x7fffu + ((u >> 16) & 1u);          // round-to-nearest-even
  return (bf16u)(u >> 16);
}
__device__ __forceinline__ float b2f(bf16u s) {
  return __uint_as_float(((uint32_t)s) << 16);
}

__device__ __forceinline__ void gload_lds16(const void* g, void* l) {
  __builtin_amdgcn_global_load_lds((__attribute__((address_space(1))) void*)(g),
                                   (__attribute__((address_space(3))) void*)(l),
                                   16, 0, 0);
}

// pack 2 f32 -> u32 of 2 bf16 (low = a, high = b), RNE
__device__ __forceinline__ unsigned cvtpk(float a, float b) {
  unsigned r;
  asm("v_cvt_pk_bf16_f32 %0, %1, %2" : "=v"(r) : "v"(a), "v"(b));
  return r;
}

// fast reciprocal (~1 ulp)
__device__ __forceinline__ float frcp(float x) {
  float r;
  asm("v_rcp_f32 %0, %1" : "=v"(r) : "v"(x));
  return r;
}

// exchange upper-half lanes of a with lower-half lanes of b (lane^32 pairing)
__device__ __forceinline__ void swap32(unsigned a, unsigned b, bool hi,
                                       unsigned& x, unsigned& y) {
#if __has_builtin(__builtin_amdgcn_permlane32_swap)
  typedef __attribute__((ext_vector_type(2))) unsigned uint2v;
  uint2v r = __builtin_amdgcn_permlane32_swap(a, b, false, false);
  x = r.x;
  y = r.y;
#else
  unsigned as = (unsigned)__shfl_xor((int)a, 32);
  unsigned bs = (unsigned)__shfl_xor((int)b, 32);
  x = hi ? bs : a;
  y = hi ? b : as;
#endif
}

// --------------------------- K0+K1 merged: convert + rearrange -------------
// blocks [0,1024): weight fp32->bf16 convert; blocks [1024,5120): rearrange.
__global__ __launch_bounds__(256) void k_pre(const float* __restrict__ w1,
                                             const float* __restrict__ w2,
                                             bf16u* __restrict__ d1,
                                             bf16u* __restrict__ d2,
                                             const float* __restrict__ x,
                                             bf16u* __restrict__ Tb) {
  if (blockIdx.x < 1024) {
    int i = blockIdx.x * 256 + threadIdx.x;
    if (i < 768 * 256) d1[i] = f2b(w1[i]);
    else { int j = i - 768 * 256; d2[j] = f2b(w2[j]); }
    return;
  }
  const int bid = blockIdx.x - 1024;
  const int ct = bid & 7, hh = (bid >> 3) & 127, b = bid >> 10;
  const int c0 = ct * 32;
  const int h1 = hh >> 3, h2 = hh & 7;
  __shared__ float tile[32][129];
  for (int e = threadIdx.x; e < 4096; e += 256) {
    int cc = e >> 7, ww = e & 127;   // coalesced x reads (512B rows)
    tile[cc][ww] = x[(((size_t)(b * 256 + c0 + cc)) * 128 + hh) * 128 + ww];
  }
  __syncthreads();
  for (int e = threadIdx.x; e < 4096; e += 256) {
    int ww = e >> 5, cc = e & 31;    // contiguous-in-c writes
    int w1i = ww >> 3, w2i = ww & 7;
    int i = ((b * 64 + h2 * 8 + w2i) << 8) | (h1 * 16 + w1i);
    Tb[(size_t)i * 256 + c0 + cc] = f2b(tile[cc][ww]);
  }
}

// --------------------------- K2: QKV GEMM (R8 form) ------------------------
// C[i,o] = sum_k Tb[i,k]*W[o,k] + bias[o]; 128x128 tile, BK=64, 4 waves (2x2)
// LDS rows = 64 bf16 = 128B (bank-period). Chunk swizzle c^(row&7) on the
// global SOURCE of global_load_lds and on ds_read (both-sides, rule #21).
// Q gets qscale*LOG2E folded in. V stored transposed [nh*32+d][kv], packed.
__global__ __launch_bounds__(256) void k_qkv(const bf16u* __restrict__ Tb,
                                             const bf16u* __restrict__ Wb,
                                             const float* __restrict__ bias,
                                             bf16u* __restrict__ Qb,
                                             bf16u* __restrict__ Kb,
                                             bf16u* __restrict__ Vtb) {
  __shared__ bf16u As[128 * 64];   // 16 KB
  __shared__ bf16u Bs[128 * 64];   // 16 KB
  // bijective XCD-chunked swizzle: 3072 blocks = 8 XCD x 384
  const int bid0 = blockIdx.x;
  const int bid = (bid0 & 7) * 384 + (bid0 >> 3);
  const int o0 = (bid % 6) * 128;          // o-tile fastest: A-panel L2 reuse
  const int i0 = (bid / 6) * 128;
  const int seg = o0 >> 8;                 // 0=Q 1=K 2=V, uniform per block
  const int t = threadIdx.x;
  const int lane = t & 63, lo = lane & 15, hi = lane >> 4;
  const int w = t >> 6, wr = w >> 1, wc = w & 1;
  const int rr = t >> 3, cc8 = t & 7;      // staging: row-in-32, chunk 0..7
  f32x4 acc[4][4] = {};
  for (int k0 = 0; k0 < 256; k0 += 64) {
    __syncthreads();
#pragma unroll
    for (int j = 0; j < 4; ++j) {
      const int row = j * 32 + rr;
      const int sc = (cc8 ^ (row & 7)) * 8;                 // swizzled source
      bf16u* const da = As + (j * 32 + w * 8) * 64;         // wave-uniform dest
      bf16u* const db = Bs + (j * 32 + w * 8) * 64;
      gload_lds16(Tb + (size_t)(i0 + row) * 256 + k0 + sc, da);
      gload_lds16(Wb + (size_t)(o0 + row) * 256 + k0 + sc, db);
    }
    __syncthreads();
#pragma unroll
    for (int ks = 0; ks < 2; ++ks) {
      bf16x8 af[4], bf_[4];
#pragma unroll
      for (int m = 0; m < 4; ++m) {
        const int row = wr * 64 + m * 16 + lo;
        const int c = (ks * 4 + hi) ^ (lo & 7);
        af[m] = *(const bf16x8*)&As[row * 64 + c * 8];
      }
#pragma unroll
      for (int nn = 0; nn < 4; ++nn) {
        const int row = wc * 64 + nn * 16 + lo;
        const int c = (ks * 4 + hi) ^ (lo & 7);
        bf_[nn] = *(const bf16x8*)&Bs[row * 64 + c * 8];
      }
#pragma unroll
      for (int m = 0; m < 4; ++m)
#pragma unroll
        for (int nn = 0; nn < 4; ++nn)
          acc[m][nn] = __builtin_amdgcn_mfma_f32_16x16x32_bf16(af[m], bf_[nn], acc[m][nn], 0, 0, 0);
    }
  }
  const float oscale = (seg == 0) ? (0.17677669529663687f * LOG2E) : 1.0f;
#pragma unroll
  for (int m = 0; m < 4; ++m) {
#pragma unroll
    for (int nn = 0; nn < 4; ++nn) {
      const int o = o0 + wc * 64 + nn * 16 + lo;
      const int within = o & 255, head = within >> 5, dd = within & 31;
      const float bia = bias[o];
      const int tok0 = i0 + wr * 64 + m * 16 + hi * 4;
      const int nt = tok0 >> 8, ls0 = tok0 & 255;
      if (seg == 2) {        // transposed [nh*32+d][kv], 4 kv contiguous -> 8B
        float v0 = acc[m][nn][0] + bia, v1 = acc[m][nn][1] + bia;
        float v2 = acc[m][nn][2] + bia, v3 = acc[m][nn][3] + bia;
        u32x2 pkd = {cvtpk(v0, v1), cvtpk(v2, v3)};
        *(u32x2*)(Vtb + ((size_t)((nt * 8 + head) * 32 + dd)) * 256 + ls0) = pkd;
      } else {
        bf16u* const dst = (seg == 0) ? Qb : Kb;
#pragma unroll
        for (int r = 0; r < 4; ++r) {
          float v = (acc[m][nn][r] + bia) * oscale;
          dst[((size_t)((nt * 8 + head) * 256 + ls0 + r)) * 32 + dd] = f2b(v);
        }
      }
    }
  }
}

// --------------------------- K3: attention (v7 + z-hoist) ------------------
// one block per (n,head); 4 independent waves x 64 q-rows (2 subtiles of 32).
// Swapped QK^T (32x32x16), unnormalized softmax (logits pre-scaled by
// qscale*LOG2E at k_qkv; max cancels). Row-sum via ones-column MFMA (accS
// lane-aligned with accO) -> no cross-lane reductions. No LDS.
__global__ __launch_bounds__(256, 2) void k_attn(const bf16u* __restrict__ Qb,
                                                 const bf16u* __restrict__ Kb,
                                                 const bf16u* __restrict__ Vtb,
                                                 bf16u* __restrict__ Ob) {
  const int nh = blockIdx.x;
  const int n = nh >> 3, h = nh & 7;
  const bf16u* Qp = Qb + (size_t)nh * 8192;
  const bf16u* Kp = Kb + (size_t)nh * 8192;
  const bf16u* Vp = Vtb + (size_t)nh * 8192;   // [32 d][256 kv]
  const int t = threadIdx.x, w = t >> 6, lane = t & 63;
  const int l31 = lane & 31;
  const bool hi5 = (lane & 32) != 0;

  // Q fragments: B-operand of QK^T.  B[k=d][col=q] = Q[q][d]
  bf16x8 qf[2][2];
#pragma unroll
  for (int qs = 0; qs < 2; ++qs)
#pragma unroll
    for (int dh = 0; dh < 2; ++dh)
      qf[qs][dh] = *(const bf16x8*)(Qp + (size_t)(w * 64 + qs * 32 + l31) * 32 +
                                    dh * 16 + (hi5 ? 8 : 0));

  // K A-frag base: A[row=kv][k=d]; V B-frag base: B[k=kv][col=d] = Vt[d][kv]
  const bf16u* kbase = Kp + (size_t)l31 * 32 + (hi5 ? 8 : 0);
  const bf16u* vbase = Vp + (size_t)l31 * 256 + (hi5 ? 8 : 0);

  bf16x8 kf0 = *(const bf16x8*)(kbase);
  bf16x8 kf1 = *(const bf16x8*)(kbase + 16);
  bf16x8 vf0 = *(const bf16x8*)(vbase);
  bf16x8 vf1 = *(const bf16x8*)(vbase + 16);

  const u32x4 onesu = {0x3f803f80u, 0x3f803f80u, 0x3f803f80u, 0x3f803f80u};
  const bf16x8 onesf = __builtin_bit_cast(bf16x8, onesu);   // bf16 1.0 x8
  const f32x16 z = {};                                      // hoisted zero C

  f32x16 accO[2] = {};
  f32x16 accS[2] = {};

#pragma unroll
  for (int kt = 0; kt < 8; ++kt) {
    // depth-1 prefetch of next K/V fragments ((kt+1)&7 wraps harmlessly)
    const int nkt = (kt + 1) & 7;
    bf16x8 nk0 = *(const bf16x8*)(kbase + nkt * 1024);
    bf16x8 nk1 = *(const bf16x8*)(kbase + nkt * 1024 + 16);
    bf16x8 nv0 = *(const bf16x8*)(vbase + nkt * 32);
    bf16x8 nv1 = *(const bf16x8*)(vbase + nkt * 32 + 16);

#pragma unroll
    for (int qs = 0; qs < 2; ++qs) {
      f32x16 s = MFMA32(kf0, qf[qs][0], z);    // C = hoisted zero (no re-init)
      s = MFMA32(kf1, qf[qs][1], s);
      // --- unnormalized softmax: p = exp2(s); pack pairs (pure streaming) ---
      unsigned pk[8];
#pragma unroll
      for (int jp = 0; jp < 8; ++jp)
        pk[jp] = cvtpk(exp2f(s[2 * jp]), exp2f(s[2 * jp + 1]));
      // --- redistribute packed P to PV A-fragment layout ---
      unsigned x0, x1, x2, x3, y0, y1, y2, y3;
      swap32(pk[0], pk[2], hi5, x0, x2);
      swap32(pk[1], pk[3], hi5, x1, x3);
      swap32(pk[4], pk[6], hi5, y0, y2);
      swap32(pk[5], pk[7], hi5, y1, y3);
      u32x4 pa0 = {x0, x1, x2, x3};
      u32x4 pa1 = {y0, y1, y2, y3};
      const bf16x8 a0 = __builtin_bit_cast(bf16x8, pa0);
      const bf16x8 a1 = __builtin_bit_cast(bf16x8, pa1);
      __builtin_amdgcn_s_setprio(1);
      accO[qs] = MFMA32(a0, vf0, accO[qs]);
      accO[qs] = MFMA32(a1, vf1, accO[qs]);
      accS[qs] = MFMA32(a0, onesf, accS[qs]);   // row-sum on matrix pipe
      accS[qs] = MFMA32(a1, onesf, accS[qs]);
      __builtin_amdgcn_s_setprio(0);
    }
    kf0 = nk0;
    kf1 = nk1;
    vf0 = nv0;
    vf1 = nv1;
  }
  // --- epilogue: normalize per-lane (accS[r] is rsum of accO[r]'s row) ---
#pragma unroll
  for (int qs = 0; qs < 2; ++qs) {
#pragma unroll
    for (int r = 0; r < 16; ++r) {
      int row = (r & 3) + 8 * (r >> 2) + ((lane & 32) >> 3);
      float o = accO[qs][r] * frcp(accS[qs][r]);
      Ob[((size_t)(n * 256 + w * 64 + qs * 32 + row)) * 256 + h * 32 + l31] = f2b(o);
    }
  }
}

// --------------------------- K4: out proj + LayerNorm (R8 form) ------------
// 64 tokens x all 256 channels per block; BK=64 + chunk swizzle; LN fused.
__global__ __launch_bounds__(256) void k_out(const bf16u* __restrict__ Ob,
                                             const bf16u* __restrict__ Wb,
                                             const float* __restrict__ bias,
                                             const float* __restrict__ lnw,
                                             const float* __restrict__ lnb,
                                             bf16u* __restrict__ On) {
  __shared__ bf16u As[64 * 64];    // 8 KB
  __shared__ bf16u Bs[256 * 64];   // 32 KB
  __shared__ float red[64][4][2];
  const int i0 = blockIdx.x * 64;
  const int t = threadIdx.x, w = t >> 6, lane = t & 63, lo = lane & 15, hi = lane >> 4;
  const int rr = t >> 3, cc8 = t & 7;
  f32x4 acc[4][4] = {};
  for (int k0 = 0; k0 < 256; k0 += 64) {
    __syncthreads();
#pragma unroll
    for (int j = 0; j < 2; ++j) {
      const int row = j * 32 + rr;
      const int sc = (cc8 ^ (row & 7)) * 8;
      gload_lds16(Ob + (size_t)(i0 + row) * 256 + k0 + sc,
                  As + (j * 32 + w * 8) * 64);
    }
#pragma unroll
    for (int j = 0; j < 8; ++j) {
      const int row = j * 32 + rr;
      const int sc = (cc8 ^ (row & 7)) * 8;
      gload_lds16(Wb + (size_t)row * 256 + k0 + sc,
                  Bs + (j * 32 + w * 8) * 64);
    }
    __syncthreads();
#pragma unroll
    for (int ks = 0; ks < 2; ++ks) {
      bf16x8 af[4], bf_[4];
#pragma unroll
      for (int m = 0; m < 4; ++m) {
        const int row = m * 16 + lo;
        const int c = (ks * 4 + hi) ^ (lo & 7);
        af[m] = *(const bf16x8*)&As[row * 64 + c * 8];
      }
#pragma unroll
      for (int nn = 0; nn < 4; ++nn) {
        const int row = w * 64 + nn * 16 + lo;
        const int c = (ks * 4 + hi) ^ (lo & 7);
        bf_[nn] = *(const bf16x8*)&Bs[row * 64 + c * 8];
      }
#pragma unroll
      for (int m = 0; m < 4; ++m)
#pragma unroll
        for (int nn = 0; nn < 4; ++nn)
          acc[m][nn] = __builtin_amdgcn_mfma_f32_16x16x32_bf16(af[m], bf_[nn], acc[m][nn], 0, 0, 0);
    }
  }
#pragma unroll
  for (int m = 0; m < 4; ++m)
#pragma unroll
    for (int nn = 0; nn < 4; ++nn) {
      float bia = bias[w * 64 + nn * 16 + lo];
#pragma unroll
      for (int r = 0; r < 4; ++r) acc[m][nn][r] += bia;
    }
#pragma unroll
  for (int m = 0; m < 4; ++m)
#pragma unroll
    for (int r = 0; r < 4; ++r) {
      float sv = acc[m][0][r] + acc[m][1][r] + acc[m][2][r] + acc[m][3][r];
      float sq = acc[m][0][r] * acc[m][0][r] + acc[m][1][r] * acc[m][1][r] +
                 acc[m][2][r] * acc[m][2][r] + acc[m][3][r] * acc[m][3][r];
      sv += __shfl_xor(sv, 1); sq += __shfl_xor(sq, 1);
      sv += __shfl_xor(sv, 2); sq += __shfl_xor(sq, 2);
      sv += __shfl_xor(sv, 4); sq += __shfl_xor(sq, 4);
      sv += __shfl_xor(sv, 8); sq += __shfl_xor(sq, 8);
      if (lo == 0) {
        red[m * 16 + hi * 4 + r][w][0] = sv;
        red[m * 16 + hi * 4 + r][w][1] = sq;
      }
    }
  __syncthreads();
#pragma unroll
  for (int m = 0; m < 4; ++m)
#pragma unroll
    for (int r = 0; r < 4; ++r) {
      int row = m * 16 + hi * 4 + r;
      float S  = red[row][0][0] + red[row][1][0] + red[row][2][0] + red[row][3][0];
      float Q2 = red[row][0][1] + red[row][1][1] + red[row][2][1] + red[row][3][1];
      float mu = S * 0.00390625f;
      float var = Q2 * 0.00390625f - mu * mu;
      float rstd = rsqrtf(var + 1e-5f);
#pragma unroll
      for (int nn = 0; nn < 4; ++nn) {
        int oc = w * 64 + nn * 16 + lo;
        float o = (acc[m][nn][r] - mu) * rstd * lnw[oc] + lnb[oc];
        On[(size_t)(i0 + row) * 256 + oc] = f2b(o);
      }
    }
}

// --------------------------- K5: inverse rearrange -------------------------
__global__ __launch_bounds__(256) void k_unrearrange(const bf16u* __restrict__ On,
                                                     float* __restrict__ y) {
  const int bid = blockIdx.x;
  const int ct = bid & 7, hh = (bid >> 3) & 127, b = bid >> 10;
  const int c0 = ct * 32;
  const int h1 = hh >> 3, h2 = hh & 7;
  __shared__ float tile[32][129];
  for (int e = threadIdx.x; e < 4096; e += 256) {
    int ww = e >> 5, cc = e & 31;
    int w1 = ww >> 3, w2 = ww & 7;
    int i = ((b * 64 + h2 * 8 + w2) << 8) | (h1 * 16 + w1);
    tile[cc][ww] = b2f(On[(size_t)i * 256 + c0 + cc]);
  }
  __syncthreads();
  for (int e = threadIdx.x; e < 4096; e += 256) {
    int cc = e >> 7, ww = e & 127;
    y[(((size_t)(b * 256 + c0 + cc)) * 128 + hh) * 128 + ww] = tile[cc][ww];
  }
}

// --------------------------- launch ----------------------------------------
extern "C" void kernel_launch(void* const* d_in, const int* in_sizes, int n_in,
                              void* d_out, int out_size, void* d_ws, size_t ws_size,
                              hipStream_t stream) {
  const float* x     = (const float*)d_in[0];
  const float* w_qkv = (const float*)d_in[1];
  const float* b_qkv = (const float*)d_in[2];
  const float* w_out = (const float*)d_in[3];
  const float* b_out = (const float*)d_in[4];
  const float* ln_w  = (const float*)d_in[5];
  const float* ln_b  = (const float*)d_in[6];
  float* y = (float*)d_out;

  const size_t SEG = 33554432;   // 16.7M bf16 elements = 32 MiB
  char* ws = (char*)d_ws;
  if (ws_size < 5 * SEG + 768 * 256 * 2 + 256 * 256 * 2) return;  // diagnostic fail
  bf16u* Tb = (bf16u*)(ws);                 // rearranged tokens; reused as On
  bf16u* Qb = (bf16u*)(ws + SEG);
  bf16u* Kb = (bf16u*)(ws + 2 * SEG);
  bf16u* Vtb = (bf16u*)(ws + 3 * SEG);      // transposed V: [nh][32 d][256 kv]
  bf16u* Ob = (bf16u*)(ws + 4 * SEG);
  bf16u* Wqkvb = (bf16u*)(ws + 5 * SEG);
  bf16u* Woutb = (bf16u*)(ws + 5 * SEG + 768 * 256 * 2);
  bf16u* On = Tb;

  k_pre<<<5120, 256, 0, stream>>>(w_qkv, w_out, Wqkvb, Woutb, x, Tb);
  k_qkv<<<3072, 256, 0, stream>>>(Tb, Wqkvb, b_qkv, Qb, Kb, Vtb);
  k_attn<<<2048, 256, 0, stream>>>(Qb, Kb, Vtb, Ob);
  k_out<<<1024, 256, 0, stream>>>(Ob, Woutb, b_out, ln_w, ln_b, On);
  k_unrearrange<<<4096, 256, 0, stream>>>(On, y);
}